// Round 1
// baseline (840.690 us; speedup 1.0000x reference)
//
#include <hip/hip_runtime.h>
#include <cstdint>

typedef unsigned short u16;
typedef __attribute__((ext_vector_type(8))) short short8;   // 8 bf16 (4 VGPRs)
typedef __attribute__((ext_vector_type(4))) float floatx4;  // MFMA C/D
typedef __attribute__((ext_vector_type(4))) float f32x4;
typedef __attribute__((ext_vector_type(8))) u16 u16x8;

static constexpr int K_DIM = 4096;
static constexpr int N_DIM = 11008;
static constexpr int NPACK = 1376;  // N/8
static constexpr int GSIZE = 128;
static constexpr int NGRP = 32;     // K/GSIZE

// fp32 -> bf16 round-to-nearest-even (raw bits)
__device__ __forceinline__ u16 f2bf(float f) {
  uint32_t u = __builtin_bit_cast(uint32_t, f);
  u += 0x7FFFu + ((u >> 16) & 1u);
  return (u16)(u >> 16);
}

// async global->LDS, 16B per lane, dest = wave-uniform base + lane*16
__device__ __forceinline__ void async16(const void* g, void* l) {
  __builtin_amdgcn_global_load_lds(
      (const __attribute__((address_space(1))) void*)g,
      (__attribute__((address_space(3))) void*)l, 16, 0, 0);
}

// ---------------------------------------------------------------------------
// x fp32 [M,K] -> bf16 [M,K]; one thread = 8 elements (16B in, 16B out)
__global__ void cvt_x_bf16(const float* __restrict__ x, u16* __restrict__ xb) {
  int t = blockIdx.x * 256 + threadIdx.x;
  const f32x4* xv = (const f32x4*)x;
  f32x4 a = xv[2 * t];
  f32x4 b = xv[2 * t + 1];
  u16x8 o;
  o[0] = f2bf(a[0]); o[1] = f2bf(a[1]); o[2] = f2bf(a[2]); o[3] = f2bf(a[3]);
  o[4] = f2bf(b[0]); o[5] = f2bf(b[1]); o[6] = f2bf(b[2]); o[7] = f2bf(b[3]);
  ((u16x8*)xb)[t] = o;
}

// ---------------------------------------------------------------------------
// qweight [K, N/8] int32 -> Wt [N, K] bf16 (dequantized, TRANSPOSED)
// thread t: k = t & (K-1) (fast), p = t >> 12  -> coalesced 2B stores along k
__global__ void dequant_wt(const int* __restrict__ qw, const int* __restrict__ qz,
                           const float* __restrict__ sc, u16* __restrict__ Wt) {
  int t = blockIdx.x * 256 + threadIdx.x;  // t < K_DIM*NPACK
  int k = t & (K_DIM - 1);
  int p = t >> 12;                         // K_DIM == 4096
  int q = qw[k * NPACK + p];
  int g = k >> 7;                          // GSIZE == 128
  int z = qz[g * NPACK + p];
  const float* scp = sc + (size_t)g * N_DIM + p * 8;
#pragma unroll
  for (int j = 0; j < 8; j++) {
    int sh = ((j & 1) << 4) | ((j >> 1) << 2);  // 0,16,4,20,8,24,12,28
    int wv = ((q >> sh) & 15) - ((z >> sh) & 15);
    Wt[(size_t)(p * 8 + j) * K_DIM + k] = f2bf((float)wv * scp[j]);
  }
}

// ---------------------------------------------------------------------------
// C[M,N] = A[M,K] * Bt[N,K]^T + bias ; bf16 inputs, fp32 out
// 128x128 tile, BK=32, 256 thr (4 waves, 2x2), each wave 4x4 of 16x16x32 MFMA
__global__ __launch_bounds__(256) void gemm_bf16(
    const u16* __restrict__ A, const u16* __restrict__ Bt,
    const float* __restrict__ bias, float* __restrict__ out, int M) {
  constexpr int BK = 32;
  __shared__ __align__(16) u16 As[128 * BK];  // 8KB, row stride 32 bf16 = 64B
  __shared__ __align__(16) u16 Bs[128 * BK];  // 8KB

  const int tid = threadIdx.x;
  const int wave = tid >> 6;
  const int lane = tid & 63;
  const int lm = lane & 15;
  const int quad = lane >> 4;
  const int m0 = blockIdx.y * 128;
  const int n0 = blockIdx.x * 128;
  const int wm = (wave & 1) * 64;
  const int wn = (wave >> 1) * 64;

  // staging: 512 chunks of 16B per tile; thread handles chunks tid, tid+256
  const int c0 = tid, c1 = tid + 256;
  const u16* gA0 = A + (size_t)(m0 + (c0 >> 2)) * K_DIM + (c0 & 3) * 8;
  const u16* gA1 = A + (size_t)(m0 + (c1 >> 2)) * K_DIM + (c1 & 3) * 8;
  const u16* gB0 = Bt + (size_t)(n0 + (c0 >> 2)) * K_DIM + (c0 & 3) * 8;
  const u16* gB1 = Bt + (size_t)(n0 + (c1 >> 2)) * K_DIM + (c1 & 3) * 8;
  u16* lA0 = As + (wave * 64) * 8;          // wave-uniform LDS bases
  u16* lA1 = As + (256 + wave * 64) * 8;
  u16* lB0 = Bs + (wave * 64) * 8;
  u16* lB1 = Bs + (256 + wave * 64) * 8;

  floatx4 acc[4][4] = {};

  for (int k0 = 0; k0 < K_DIM; k0 += BK) {
    async16(gA0, lA0);
    async16(gA1, lA1);
    async16(gB0, lB0);
    async16(gB1, lB1);
    gA0 += BK; gA1 += BK; gB0 += BK; gB1 += BK;
    __syncthreads();  // waitcnt vmcnt(0) + barrier: staging visible

    short8 af[4], bfr[4];
#pragma unroll
    for (int i = 0; i < 4; i++)
      af[i] = *(const short8*)&As[(wm + i * 16 + lm) * BK + quad * 8];
#pragma unroll
    for (int j = 0; j < 4; j++)
      bfr[j] = *(const short8*)&Bs[(wn + j * 16 + lm) * BK + quad * 8];
#pragma unroll
    for (int i = 0; i < 4; i++)
#pragma unroll
      for (int j = 0; j < 4; j++)
        acc[i][j] = __builtin_amdgcn_mfma_f32_16x16x32_bf16(af[i], bfr[j],
                                                            acc[i][j], 0, 0, 0);
    __syncthreads();  // protect LDS from next iteration's staging
  }

  // epilogue: C/D layout col=lane&15, row=quad*4+reg
  const int colb = n0 + wn + lm;
#pragma unroll
  for (int j = 0; j < 4; j++) {
    float bj = bias[colb + j * 16];
#pragma unroll
    for (int i = 0; i < 4; i++) {
      int row = m0 + wm + i * 16 + quad * 4;
#pragma unroll
      for (int r = 0; r < 4; r++)
        out[(size_t)(row + r) * N_DIM + colb + j * 16] = acc[i][j][r] + bj;
    }
  }
}

// ---------------------------------------------------------------------------
// fallback (only if workspace too small): 1 thread / output, fp32
__global__ void naive_gemm(const float* __restrict__ x, const int* __restrict__ qw,
                           const int* __restrict__ qz, const float* __restrict__ sc,
                           const float* __restrict__ bias, float* __restrict__ out,
                           int M) {
  long long idx = (long long)blockIdx.x * 256 + threadIdx.x;
  if (idx >= (long long)M * N_DIM) return;
  int m = (int)(idx / N_DIM);
  int n = (int)(idx % N_DIM);
  int p = n >> 3, j = n & 7;
  int sh = ((j & 1) << 4) | ((j >> 1) << 2);
  float acc = 0.f;
  for (int g = 0; g < NGRP; g++) {
    float s = sc[(size_t)g * N_DIM + n];
    int z = (qz[g * NPACK + p] >> sh) & 15;
    float part = 0.f;
    for (int kk = 0; kk < GSIZE; kk++) {
      int k = g * GSIZE + kk;
      int w = ((qw[(size_t)k * NPACK + p] >> sh) & 15) - z;
      part += x[(size_t)m * K_DIM + k] * (float)w;
    }
    acc += part * s;
  }
  out[idx] = acc + bias[n];
}

// ---------------------------------------------------------------------------
extern "C" void kernel_launch(void* const* d_in, const int* in_sizes, int n_in,
                              void* d_out, int out_size, void* d_ws, size_t ws_size,
                              hipStream_t stream) {
  const float* x = (const float*)d_in[0];
  const int* qw = (const int*)d_in[1];
  const int* qz = (const int*)d_in[2];
  const float* sc = (const float*)d_in[3];
  const float* bias = (const float*)d_in[4];
  float* out = (float*)d_out;
  const int M = in_sizes[0] / K_DIM;  // 4096 (B*S)

  size_t xb_bytes = (size_t)M * K_DIM * 2;           // 33.5 MB
  size_t wt_bytes = (size_t)K_DIM * N_DIM * 2;       // 90.2 MB

  if (ws_size >= xb_bytes + wt_bytes && (M % 128) == 0) {
    u16* xb = (u16*)d_ws;
    u16* Wt = (u16*)((char*)d_ws + xb_bytes);
    int cvt_blocks = (M * (K_DIM / 8)) / 256;        // exact: M%128==0
    cvt_x_bf16<<<cvt_blocks, 256, 0, stream>>>(x, xb);
    dequant_wt<<<(K_DIM * NPACK) / 256, 256, 0, stream>>>(qw, qz, sc, Wt);
    gemm_bf16<<<dim3(N_DIM / 128, M / 128), 256, 0, stream>>>(xb, Wt, bias, out, M);
  } else {
    long long total = (long long)M * N_DIM;
    naive_gemm<<<(int)((total + 255) / 256), 256, 0, stream>>>(x, qw, qz, sc, bias,
                                                               out, M);
  }
}

// Round 2
// 661.393 us; speedup vs baseline: 1.2711x; 1.2711x over previous
//
#include <hip/hip_runtime.h>
#include <cstdint>

typedef unsigned short u16;
typedef __attribute__((ext_vector_type(8))) short short8;   // 8 bf16 (4 VGPRs)
typedef __attribute__((ext_vector_type(4))) float floatx4;  // MFMA C/D
typedef __attribute__((ext_vector_type(4))) float f32x4;
typedef __attribute__((ext_vector_type(8))) u16 u16x8;

static constexpr int K_DIM = 4096;
static constexpr int N_DIM = 11008;
static constexpr int NPACK = 1376;  // N/8
static constexpr int GSIZE = 128;
static constexpr int NGRP = 32;     // K/GSIZE

// fp32 -> bf16 round-to-nearest-even (raw bits)
__device__ __forceinline__ u16 f2bf(float f) {
  uint32_t u = __builtin_bit_cast(uint32_t, f);
  u += 0x7FFFu + ((u >> 16) & 1u);
  return (u16)(u >> 16);
}

// async global->LDS, 16B per lane, dest = wave-uniform base + lane*16
__device__ __forceinline__ void async16(const void* g, void* l) {
  __builtin_amdgcn_global_load_lds(
      (const __attribute__((address_space(1))) void*)g,
      (__attribute__((address_space(3))) void*)l, 16, 0, 0);
}

// ---------------------------------------------------------------------------
// x fp32 [M,K] -> bf16 [M,K]; one thread = 8 elements (16B in, 16B out)
__global__ void cvt_x_bf16(const float* __restrict__ x, u16* __restrict__ xb) {
  int t = blockIdx.x * 256 + threadIdx.x;
  const f32x4* xv = (const f32x4*)x;
  f32x4 a = xv[2 * t];
  f32x4 b = xv[2 * t + 1];
  u16x8 o;
  o[0] = f2bf(a[0]); o[1] = f2bf(a[1]); o[2] = f2bf(a[2]); o[3] = f2bf(a[3]);
  o[4] = f2bf(b[0]); o[5] = f2bf(b[1]); o[6] = f2bf(b[2]); o[7] = f2bf(b[3]);
  ((u16x8*)xb)[t] = o;
}

// ---------------------------------------------------------------------------
// qweight [K, N/8] int32 -> Wt [N, K] bf16 (dequantized, TRANSPOSED)
// LDS-transposed: coalesced dword loads of a 128k x 32p tile, then
// wave-contiguous 128B bf16 stores along k. Row stride 33 -> no bank conflicts.
__global__ __launch_bounds__(256) void dequant_wt(
    const int* __restrict__ qw, const int* __restrict__ qz,
    const float* __restrict__ sc, u16* __restrict__ Wt) {
  constexpr int KT = 128, PT = 32, LSTR = PT + 1;
  __shared__ int pk[KT * LSTR];   // 16.5 KB, [k][p] padded
  __shared__ float scs[PT * 8];   // 1 KB
  __shared__ int zs[PT];

  const int tid = threadIdx.x;
  const int p0 = blockIdx.x * PT;   // 43 blocks
  const int k0 = blockIdx.y * KT;   // 32 blocks
  const int g = k0 >> 7;            // KT == GSIZE: one group per tile

#pragma unroll
  for (int i = 0; i < 16; i++) {    // 4096 ints, coalesced (128B rows)
    int idx = tid + i * 256;
    int r = idx >> 5, c = idx & 31;
    pk[r * LSTR + c] = qw[(size_t)(k0 + r) * NPACK + p0 + c];
  }
  if (tid < PT) zs[tid] = qz[g * NPACK + p0 + tid];
  if (tid < PT * 8) scs[tid] = sc[(size_t)g * N_DIM + p0 * 8 + tid];
  __syncthreads();

  const int wave = tid >> 6, lane = tid & 63;
#pragma unroll 4
  for (int i = 0; i < 64; i++) {
    int nl = wave * 64 + i;         // 0..255 (wave-uniform)
    int c = nl >> 3, j = nl & 7;
    int sh = ((j & 1) << 4) | ((j >> 1) << 2);  // 0,16,4,20,8,24,12,28
    int zv = (zs[c] >> sh) & 15;
    float s = scs[c * 8 + j];
    int q1 = pk[lane * LSTR + c];          // k = lane   (conflict-free)
    int q2 = pk[(lane + 64) * LSTR + c];   // k = lane+64
    size_t ob = (size_t)(p0 * 8 + nl) * K_DIM + k0;
    Wt[ob + lane] = f2bf((float)(((q1 >> sh) & 15) - zv) * s);
    Wt[ob + 64 + lane] = f2bf((float)(((q2 >> sh) & 15) - zv) * s);
  }
}

// ---------------------------------------------------------------------------
// C[M,N] = A[M,K] * Bt[N,K]^T + bias ; bf16 inputs, fp32 out
// 128x128 tile, BK=32, 256 thr (4 waves, 2x2), each wave 4x4 of 16x16x32 MFMA
// 1-D grid + XCD-aware swizzle: xcd = f&7 owns m-band [xcd*h, xcd*h+h),
// m-fastest within band -> per-XCD L2 holds h A-panels + 1 streaming B panel.
__global__ __launch_bounds__(256) void gemm_bf16(
    const u16* __restrict__ A, const u16* __restrict__ Bt,
    const float* __restrict__ bias, float* __restrict__ out, int Mb) {
  constexpr int BK = 32;
  __shared__ __align__(16) u16 As[128 * BK];  // 8KB
  __shared__ __align__(16) u16 Bs[128 * BK];  // 8KB

  const int f = blockIdx.x;
  int mb, nb;
  if ((Mb & 7) == 0) {
    int h = Mb >> 3;
    int xcd = f & 7;
    int s = f >> 3;
    mb = xcd * h + (s % h);
    nb = s / h;
  } else {
    mb = f % Mb;
    nb = f / Mb;
  }
  const int m0 = mb * 128;
  const int n0 = nb * 128;

  const int tid = threadIdx.x;
  const int wave = tid >> 6;
  const int lane = tid & 63;
  const int lm = lane & 15;
  const int quad = lane >> 4;
  const int wm = (wave & 1) * 64;
  const int wn = (wave >> 1) * 64;

  // staging: 512 chunks of 16B per tile; thread handles chunks tid, tid+256
  const int c0 = tid, c1 = tid + 256;
  const u16* gA0 = A + (size_t)(m0 + (c0 >> 2)) * K_DIM + (c0 & 3) * 8;
  const u16* gA1 = A + (size_t)(m0 + (c1 >> 2)) * K_DIM + (c1 & 3) * 8;
  const u16* gB0 = Bt + (size_t)(n0 + (c0 >> 2)) * K_DIM + (c0 & 3) * 8;
  const u16* gB1 = Bt + (size_t)(n0 + (c1 >> 2)) * K_DIM + (c1 & 3) * 8;
  u16* lA0 = As + (wave * 64) * 8;          // wave-uniform LDS bases
  u16* lA1 = As + (256 + wave * 64) * 8;
  u16* lB0 = Bs + (wave * 64) * 8;
  u16* lB1 = Bs + (256 + wave * 64) * 8;

  floatx4 acc[4][4] = {};

  for (int k0i = 0; k0i < K_DIM; k0i += BK) {
    async16(gA0, lA0);
    async16(gA1, lA1);
    async16(gB0, lB0);
    async16(gB1, lB1);
    gA0 += BK; gA1 += BK; gB0 += BK; gB1 += BK;
    __syncthreads();  // waitcnt vmcnt(0) + barrier: staging visible

    short8 af[4], bfr[4];
#pragma unroll
    for (int i = 0; i < 4; i++)
      af[i] = *(const short8*)&As[(wm + i * 16 + lm) * BK + quad * 8];
#pragma unroll
    for (int j = 0; j < 4; j++)
      bfr[j] = *(const short8*)&Bs[(wn + j * 16 + lm) * BK + quad * 8];
#pragma unroll
    for (int i = 0; i < 4; i++)
#pragma unroll
      for (int j = 0; j < 4; j++)
        acc[i][j] = __builtin_amdgcn_mfma_f32_16x16x32_bf16(af[i], bfr[j],
                                                            acc[i][j], 0, 0, 0);
    __syncthreads();  // protect LDS from next iteration's staging
  }

  // epilogue: C/D layout col=lane&15, row=quad*4+reg
  const int colb = n0 + wn + lm;
#pragma unroll
  for (int j = 0; j < 4; j++) {
    float bj = bias[colb + j * 16];
#pragma unroll
    for (int i = 0; i < 4; i++) {
      int row = m0 + wm + i * 16 + quad * 4;
#pragma unroll
      for (int r = 0; r < 4; r++)
        out[(size_t)(row + r) * N_DIM + colb + j * 16] = acc[i][j][r] + bj;
    }
  }
}

// ---------------------------------------------------------------------------
// fallback (only if workspace too small): 1 thread / output, fp32
__global__ void naive_gemm(const float* __restrict__ x, const int* __restrict__ qw,
                           const int* __restrict__ qz, const float* __restrict__ sc,
                           const float* __restrict__ bias, float* __restrict__ out,
                           int M) {
  long long idx = (long long)blockIdx.x * 256 + threadIdx.x;
  if (idx >= (long long)M * N_DIM) return;
  int m = (int)(idx / N_DIM);
  int n = (int)(idx % N_DIM);
  int p = n >> 3, j = n & 7;
  int sh = ((j & 1) << 4) | ((j >> 1) << 2);
  float acc = 0.f;
  for (int g = 0; g < NGRP; g++) {
    float s = sc[(size_t)g * N_DIM + n];
    int z = (qz[g * NPACK + p] >> sh) & 15;
    float part = 0.f;
    for (int kk = 0; kk < GSIZE; kk++) {
      int k = g * GSIZE + kk;
      int w = ((qw[(size_t)k * NPACK + p] >> sh) & 15) - z;
      part += x[(size_t)m * K_DIM + k] * (float)w;
    }
    acc += part * s;
  }
  out[idx] = acc + bias[n];
}

// ---------------------------------------------------------------------------
extern "C" void kernel_launch(void* const* d_in, const int* in_sizes, int n_in,
                              void* d_out, int out_size, void* d_ws, size_t ws_size,
                              hipStream_t stream) {
  const float* x = (const float*)d_in[0];
  const int* qw = (const int*)d_in[1];
  const int* qz = (const int*)d_in[2];
  const float* sc = (const float*)d_in[3];
  const float* bias = (const float*)d_in[4];
  float* out = (float*)d_out;
  const int M = in_sizes[0] / K_DIM;  // 4096 (B*S)

  size_t xb_bytes = (size_t)M * K_DIM * 2;           // 33.5 MB
  size_t wt_bytes = (size_t)K_DIM * N_DIM * 2;       // 90.2 MB

  if (ws_size >= xb_bytes + wt_bytes && (M % 128) == 0) {
    u16* xb = (u16*)d_ws;
    u16* Wt = (u16*)((char*)d_ws + xb_bytes);
    int cvt_blocks = (M * (K_DIM / 8)) / 256;        // exact: M%128==0
    cvt_x_bf16<<<cvt_blocks, 256, 0, stream>>>(x, xb);
    dequant_wt<<<dim3(NPACK / 32, K_DIM / 128), 256, 0, stream>>>(qw, qz, sc, Wt);
    int Mb = M / 128;
    gemm_bf16<<<dim3(Mb * (N_DIM / 128)), 256, 0, stream>>>(xb, Wt, bias, out, Mb);
  } else {
    long long total = (long long)M * N_DIM;
    naive_gemm<<<(int)((total + 255) / 256), 256, 0, stream>>>(x, qw, qz, sc, bias,
                                                               out, M);
  }
}